// Round 1
// baseline (313.327 us; speedup 1.0000x reference)
//
#include <hip/hip_runtime.h>
#include <hip/hip_bf16.h>
#include <math.h>

#define BATCH 16
#define CIN   128
#define COUT  256
#define HH    56
#define WW    56
#define HW    3136
#define NTAP  9
#define NE    (COUT*CIN*NTAP)   // 294912

typedef short short8 __attribute__((ext_vector_type(8)));
typedef float floatx4 __attribute__((ext_vector_type(4)));

// workspace layout (byte offsets, all 256-aligned)
#define WSB_CTX   0                          // fp32 [16][128]
#define WSB_ASP   8192                       // fp32 [16][16] (9 used)
#define WSB_AIN   9472                       // fp32 [16][128]
#define WSB_AOUT  17664                      // fp32 [16][256]
#define WSB_ZP    34048                      // 4096 B of zeros (conv halo source)
#define WSB_XT    38144                      // bf16 [16][3136][128]
#define WSB_DYN   (WSB_XT + BATCH*HW*CIN*2)  // bf16 [16][9][256][128]  (tap,oc,ic)

// fp32 -> bf16 RNE
static __device__ inline unsigned short f2b(float f) {
    union { float f; unsigned u; } v; v.f = f;
    unsigned r = v.u + 0x7FFF + ((v.u >> 16) & 1);
    return (unsigned short)(r >> 16);
}
static __device__ inline short8 pack8(float4 a, float4 b) {
    short8 r;
    r[0] = (short)f2b(a.x); r[1] = (short)f2b(a.y); r[2] = (short)f2b(a.z); r[3] = (short)f2b(a.w);
    r[4] = (short)f2b(b.x); r[5] = (short)f2b(b.y); r[6] = (short)f2b(b.z); r[7] = (short)f2b(b.w);
    return r;
}

// async global->LDS, 16B per lane; LDS dst = wave-uniform base + lane*16
typedef const __attribute__((address_space(1))) void* gas_ptr;
typedef __attribute__((address_space(3))) void* las_ptr;
static __device__ __forceinline__ void gl_lds16(const void* g, void* l) {
    __builtin_amdgcn_global_load_lds((gas_ptr)g, (las_ptr)l, 16, 0, 0);
}

// ---------------------------------------------------------------------------
// K1: context[b,c] = mean(x[b,c,:,:]); block 0 also zeroes the conv zero-page
__global__ void k_context(const float* __restrict__ x, float* __restrict__ ctx,
                          float* __restrict__ zp) {
    int bc = blockIdx.x;
    if (bc == 0 && threadIdx.x < 64) {
        uint4 z = {0u, 0u, 0u, 0u};
        ((uint4*)zp)[threadIdx.x] = z;   // 1024 B of zeros
    }
    const float4* p = (const float4*)(x + (size_t)bc * HW);
    float s = 0.f;
    for (int i = threadIdx.x; i < HW / 4; i += 256) { float4 v = p[i]; s += v.x + v.y + v.z + v.w; }
    for (int off = 32; off; off >>= 1) s += __shfl_down(s, off, 64);
    __shared__ float red[4];
    if ((threadIdx.x & 63) == 0) red[threadIdx.x >> 6] = s;
    __syncthreads();
    if (threadIdx.x == 0) ctx[bc] = (red[0] + red[1] + red[2] + red[3]) * (1.f / (float)HW);
}

// ---------------------------------------------------------------------------
// K2: small gates — one wave per GEMV row
__global__ void k_attn(const float* __restrict__ ctx,
                       const float* __restrict__ wsp, const float* __restrict__ bsp,
                       const float* __restrict__ win, const float* __restrict__ bin,
                       const float* __restrict__ wout, const float* __restrict__ bout,
                       float* __restrict__ asp, float* __restrict__ ain, float* __restrict__ aout) {
    int R = blockIdx.x * 4 + (threadIdx.x >> 6);
    int lane = threadIdx.x & 63;
    int b = R / 393, r = R % 393;
    const float* w; float bias; float* o;
    if (r < 9)        { w = wsp  + r * CIN;         bias = bsp[r];         o = asp  + b * 16  + r; }
    else if (r < 137) { w = win  + (r - 9) * CIN;   bias = bin[r - 9];     o = ain  + b * CIN + (r - 9); }
    else              { w = wout + (r - 137) * CIN; bias = bout[r - 137];  o = aout + b * COUT + (r - 137); }
    float2 wv = ((const float2*)w)[lane];
    float2 cv = ((const float2*)(ctx + b * CIN))[lane];
    float d = wv.x * cv.x + wv.y * cv.y;
    for (int off = 32; off; off >>= 1) d += __shfl_down(d, off, 64);
    if (lane == 0) *o = 1.f / (1.f + __expf(-(d + bias)));
}

// ---------------------------------------------------------------------------
// K3 fat kernel: blocks [0,784) do the x transpose+cast (xt), blocks
// [784, 784+1152) do the dyn build (independent work, overlapped in one launch).
#define XT_BLOCKS    784          // 49 * 16
#define BUILD_BLOCKS 1152         // NE / 256
__global__ void k_fat(const float* __restrict__ x, unsigned short* __restrict__ xt,
                      const float* __restrict__ ctx, const float* __restrict__ wk,
                      const float* __restrict__ bk, const float* __restrict__ base,
                      const float* __restrict__ asp, const float* __restrict__ ain,
                      const float* __restrict__ aout, unsigned short* __restrict__ dyn) {
    if (blockIdx.x < XT_BLOCKS) {
        // ---- xt: [b][pix][ic] bf16; thread: 1 pixel x 32 ic ----
        int bid = blockIdx.x;
        int b = bid / 49;
        int p = (bid % 49) * 64 + (threadIdx.x & 63);
        int icq = threadIdx.x >> 6;
        const float* xb = x + (size_t)b * CIN * HW + p;
        unsigned short tmp[32];
#pragma unroll
        for (int j = 0; j < 32; ++j) tmp[j] = f2b(xb[(size_t)(icq * 32 + j) * HW]);
        uint4* dst = (uint4*)(xt + ((size_t)b * HW + p) * CIN + icq * 32);
        const uint4* s = (const uint4*)tmp;
        dst[0] = s[0]; dst[1] = s[1]; dst[2] = s[2]; dst[3] = s[3];
        return;
    }
    // ---- build: skinny MFMA GEMM, 64 n per wave (4 frags of 16) ----
    int bid = blockIdx.x - XT_BLOCKS;
    int wid = threadIdx.x >> 6, l = threadIdx.x & 63;
    int lq = l & 15, quad = l >> 4;
    short8 afr[4];
    const float* arow = ctx + lq * CIN;
#pragma unroll
    for (int kc = 0; kc < 4; ++kc) {
        float4 v0 = *(const float4*)(arow + kc * 32 + quad * 8);
        float4 v1 = *(const float4*)(arow + kc * 32 + quad * 8 + 4);
        afr[kc] = pack8(v0, v1);
    }
    int n0w = bid * 256 + wid * 64;
    for (int nf = 0; nf < 4; ++nf) {
        int n0 = n0w + nf * 16;
        int ic  = (n0 & 127) + lq;
        int oc  = (n0 >> 7) & 255;
        int tap = n0 >> 15;
        int e = (oc * CIN + ic) * NTAP + tap;
        const float* wrow = wk + (size_t)e * CIN;
        floatx4 acc = {0.f, 0.f, 0.f, 0.f};
#pragma unroll
        for (int kc = 0; kc < 4; ++kc) {
            float4 v0 = *(const float4*)(wrow + kc * 32 + quad * 8);
            float4 v1 = *(const float4*)(wrow + kc * 32 + quad * 8 + 4);
            short8 bfr = pack8(v0, v1);
            acc = __builtin_amdgcn_mfma_f32_16x16x32_bf16(afr[kc], bfr, acc, 0, 0, 0);
        }
        float bke = bk[e], bse = base[e];
#pragma unroll
        for (int r = 0; r < 4; ++r) {
            int b = quad * 4 + r;
            float s = 1.f / (1.f + __expf(-(acc[r] + bke)));
            float v = bse * s * aout[b * COUT + oc] * ain[b * CIN + ic] * asp[b * 16 + tap];
            dyn[(size_t)b * NE + n0 + lq] = f2b(v);
        }
    }
}

// ---------------------------------------------------------------------------
// K4: conv as MFMA implicit GEMM. 448 blocks, XCD-swizzled. Block: 64 oc x 8
// output rows. Staging now via global_load_lds width=16 (no VGPR round-trip,
// no ds_write bank conflicts):
//   s_x: [ry 0..9][col 0..63][32 ic], 64-B rows; col j holds gx = j-1; cols
//        beyond gx=55 / halo gx=-1 / OOB gy rows are sourced from a zero page
//        so every lane always issues its DMA (no exec-mask subtleties).
//   s_a: [tap*64+oc][32 ic] — destination already linear in (wave, lane).
// 2 barriers per ic-chunk; setprio(1) around the MFMA tap loop (T5).
__global__ __launch_bounds__(256, 2) void k_conv(
    const unsigned short* __restrict__ xt, const unsigned short* __restrict__ dyn,
    const float* __restrict__ bias, float* __restrict__ out,
    const unsigned short* __restrict__ zp) {
    __shared__ char s_x[640 * 64];   // 40 KiB
    __shared__ char s_a[576 * 64];   // 36 KiB
    // decode swizzled id: p = oc*16 + b (pair), r = row-block
    int id  = blockIdx.x;
    int low = id & 7;
    int q   = id >> 3;
    int r   = q % 7;
    int phi = q / 7;
    int p   = phi * 8 + low;
    int oc0 = (p >> 4) * 64;
    int b   = p & 15;
    int r0  = r * 8;

    int tid = threadIdx.x;
    int wn = tid >> 6, l = tid & 63, lq = l & 15, quad = l >> 4;
    const unsigned short* xtb  = xt  + (size_t)b * HW * CIN;
    const unsigned short* dynb = dyn + (size_t)b * NE;

    // x-stage geometry: this lane covers (col = wn*16 + l/4, icq = l&3);
    // LDS dst byte = ry*4096 + wn*1024 + l*16  (wave-uniform base + lane*16)
    int colx = wn * 16 + (l >> 2);
    int gxs  = colx - 1;
    bool gxok = (unsigned)gxs < (unsigned)WW;
    const unsigned short* zsrc = zp + l * 8;   // 16 B of zeros per lane

    int pixaddr[7];
#pragma unroll
    for (int nf = 0; nf < 7; ++nf) {
        int n = nf * 16 + lq;                       // 0..111 within wave's 2 rows
        int tr = wn * 2 + n / 56, col = n % 56;
        pixaddr[nf] = (tr * 64 + col) * 64 + quad * 16;
    }

    floatx4 acc[4][7];
#pragma unroll
    for (int i = 0; i < 4; ++i)
#pragma unroll
        for (int j = 0; j < 7; ++j) acc[i][j] = (floatx4){0.f, 0.f, 0.f, 0.f};

    for (int kc = 0; kc < 4; ++kc) {
        __syncthreads();
        // stage x tile: 10 rows x 64 cols x 32 ic, one DMA per wave per row
#pragma unroll
        for (int ry = 0; ry < 10; ++ry) {
            int gy = r0 + ry - 1;
            const unsigned short* src =
                (gxok && (unsigned)gy < (unsigned)HH)
                    ? xtb + (size_t)(gy * WW + gxs) * CIN + kc * 32 + (l & 3) * 8
                    : zsrc;
            gl_lds16(src, s_x + ry * 4096 + wn * 1024);
        }
        // stage A tile: all 9 taps x 64 oc x 32 ic (dst linear: u*16)
#pragma unroll
        for (int i = 0; i < 9; ++i) {
            int u = i * 256 + tid;
            int icq2 = u & 3, oc = (u >> 2) & 63, tap = u >> 8;
            gl_lds16(dynb + (size_t)(tap * COUT + oc0 + oc) * CIN + kc * 32 + icq2 * 8,
                     s_a + i * 4096 + wn * 1024);
        }
        __syncthreads();
        __builtin_amdgcn_s_setprio(1);
#pragma unroll
        for (int tap = 0; tap < 9; ++tap) {
            short8 af[4];
#pragma unroll
            for (int mf = 0; mf < 4; ++mf)
                af[mf] = *(const short8*)(s_a + (tap * 64 + mf * 16 + lq) * 64 + quad * 16);
            int toff = (tap / 3) * 4096 + (tap % 3) * 64;
#pragma unroll
            for (int nf = 0; nf < 7; ++nf) {
                short8 bf = *(const short8*)(s_x + pixaddr[nf] + toff);
#pragma unroll
                for (int mf = 0; mf < 4; ++mf)
                    acc[mf][nf] = __builtin_amdgcn_mfma_f32_16x16x32_bf16(af[mf], bf, acc[mf][nf], 0, 0, 0);
            }
        }
        __builtin_amdgcn_s_setprio(0);
    }

    // epilogue: D[m=quad*4+r][n=lq]
#pragma unroll
    for (int mf = 0; mf < 4; ++mf) {
#pragma unroll
        for (int rr = 0; rr < 4; ++rr) {
            int oc = oc0 + mf * 16 + quad * 4 + rr;
            float bs = bias[oc];
            float* ob = out + (size_t)(b * COUT + oc) * HW + (r0 + wn * 2) * 56 + lq;
#pragma unroll
            for (int nf = 0; nf < 7; ++nf)
                ob[nf * 16] = acc[mf][nf][rr] + bs;
        }
    }
}

// ---------------------------------------------------------------------------
extern "C" void kernel_launch(void* const* d_in, const int* in_sizes, int n_in,
                              void* d_out, int out_size, void* d_ws, size_t ws_size,
                              hipStream_t stream) {
    const float* x    = (const float*)d_in[0];
    const float* base = (const float*)d_in[1];
    const float* bias = (const float*)d_in[2];
    const float* wsp  = (const float*)d_in[3];
    const float* bsp  = (const float*)d_in[4];
    const float* win  = (const float*)d_in[5];
    const float* bin  = (const float*)d_in[6];
    const float* wout = (const float*)d_in[7];
    const float* bout = (const float*)d_in[8];
    const float* wk   = (const float*)d_in[9];
    const float* bk   = (const float*)d_in[10];
    float* out = (float*)d_out;
    char* ws = (char*)d_ws;

    float* ctx  = (float*)(ws + WSB_CTX);
    float* asp  = (float*)(ws + WSB_ASP);
    float* ain  = (float*)(ws + WSB_AIN);
    float* aout = (float*)(ws + WSB_AOUT);
    float* zp   = (float*)(ws + WSB_ZP);
    unsigned short* xt  = (unsigned short*)(ws + WSB_XT);
    unsigned short* dyn = (unsigned short*)(ws + WSB_DYN);

    k_context<<<BATCH * CIN, 256, 0, stream>>>(x, ctx, zp);
    k_attn<<<(BATCH * 393) / 4, 256, 0, stream>>>(ctx, wsp, bsp, win, bin, wout, bout, asp, ain, aout);
    k_fat<<<XT_BLOCKS + BUILD_BLOCKS, 256, 0, stream>>>(x, xt, ctx, wk, bk, base, asp, ain, aout, dyn);
    k_conv<<<448, 256, 0, stream>>>(xt, dyn, bias, out, (const unsigned short*)zp);
}